// Round 1
// baseline (345.654 us; speedup 1.0000x reference)
//
#include <hip/hip_runtime.h>

typedef unsigned short u16;
typedef unsigned int u32;
using short8  = __attribute__((ext_vector_type(8))) short;
using floatx4 = __attribute__((ext_vector_type(4))) float;

#define N_TOK   2048
#define D_MODEL 1024
#define D_INT   512
#define NE      8
#define NPAIR   (N_TOK * 2)
#define ROWS_PAD 5120   // >= 4096 + 8*127, multiple of 128

// ws layout (bytes)
#define O_META   0          // int meta[64]: [0..8]=off_pad, [16..23]=cursor
#define O_ROWOF  4096       // int row_of[4096]
#define O_XG     65536      // u16 Xg[5120*1024]
#define O_ACT    10551296   // u16 Act[5120*512]
#define O_O2     15794176   // float O2[5120*1024]
#define O_FC1B   36765696   // u16 fc1b[8*1024*1024]
#define O_FC2B   53542912   // u16 fc2b[8*1024*512]

static __device__ inline u16 f2bf(float f) {
    u32 u = __builtin_bit_cast(u32, f);
    u = (u + 0x7fffu + ((u >> 16) & 1u)) >> 16;
    return (u16)u;
}
static __device__ inline u32 pack2(float a, float b) {
    return (u32)f2bf(a) | ((u32)f2bf(b) << 16);
}

__global__ void setup_kernel(const int* __restrict__ counts, int* __restrict__ meta) {
    if (threadIdx.x == 0) {
        int acc = 0;
        for (int e = 0; e < NE; e++) {
            meta[e] = acc;
            acc += ((counts[e] + 127) >> 7) << 7;
        }
        meta[8] = acc;
    }
    if (threadIdx.x < NE) meta[16 + threadIdx.x] = 0;
}

__global__ void dispatch_gather(const float* __restrict__ x,
                                const int* __restrict__ indices,
                                int* __restrict__ meta,
                                int* __restrict__ row_of,
                                u16* __restrict__ Xg) {
    int p = blockIdx.x;          // 0..4095 (t,k) pair
    __shared__ int srow;
    if (threadIdx.x == 0) {
        int e   = indices[p];
        int pos = atomicAdd(&meta[16 + e], 1);
        int row = meta[e] + pos;
        row_of[p] = row;
        srow = row;
    }
    __syncthreads();
    int row = srow;
    int t = p >> 1;
    const floatx4* src = reinterpret_cast<const floatx4*>(x + (size_t)t * D_MODEL);
    floatx4 a = src[threadIdx.x * 2];
    floatx4 b = src[threadIdx.x * 2 + 1];
    uint4 o;
    o.x = pack2(a[0], a[1]); o.y = pack2(a[2], a[3]);
    o.z = pack2(b[0], b[1]); o.w = pack2(b[2], b[3]);
    *reinterpret_cast<uint4*>(Xg + (size_t)row * D_MODEL + threadIdx.x * 8) = o;
}

// fc1: 8*1024*1024 f32 -> bf16 ; fc2: 8*1024*512
__global__ void convert_w(const float* __restrict__ fc1, const float* __restrict__ fc2,
                          u16* __restrict__ fc1b, u16* __restrict__ fc2b) {
    size_t v = (size_t)blockIdx.x * 256 + threadIdx.x;   // vec8 id, total 1572864
    const float* src; u16* dst; size_t off;
    if (v < 1048576) { src = fc1; dst = fc1b; off = v * 8; }
    else             { src = fc2; dst = fc2b; off = (v - 1048576) * 8; }
    const floatx4* s4 = reinterpret_cast<const floatx4*>(src + off);
    floatx4 a = s4[0], b = s4[1];
    uint4 o;
    o.x = pack2(a[0], a[1]); o.y = pack2(a[2], a[3]);
    o.z = pack2(b[0], b[1]); o.w = pack2(b[2], b[3]);
    *reinterpret_cast<uint4*>(dst + off) = o;
}

// GEMM1: [rows x 1024] * fc1[e]^T -> h[rows x 1024]; a = y*silu(z) -> Act[rows x 512] bf16
// grid (8, 40): x = 64-wide g block, y = 128-row tile
__global__ __launch_bounds__(256) void gemm1_kernel(
    const u16* __restrict__ Xg, const u16* __restrict__ fc1b,
    u16* __restrict__ Act, const int* __restrict__ meta) {
    __shared__ u16 As[4096];   // [kb][row][8]
    __shared__ u16 Bs[4096];
    __shared__ int soff[9];
    int tid = threadIdx.x;
    if (tid < 9) soff[tid] = meta[tid];
    __syncthreads();
    int row0 = blockIdx.y * 128;
    if (row0 >= soff[8]) return;
    int e = 0;
    while (soff[e + 1] <= row0) e++;
    int bx = blockIdx.x;                       // g block: g in [bx*64, bx*64+64)
    const u16* A  = Xg + (size_t)row0 * 1024;
    const u16* Be = fc1b + (size_t)e * 1024 * 1024;

    int lane = tid & 63, w = tid >> 6;
    int m0 = (w >> 1) * 64, n0 = (w & 1) * 32;
    int lr = lane & 15, kq = lane >> 4;

    floatx4 acc[4][4];
    #pragma unroll
    for (int i = 0; i < 4; i++)
        #pragma unroll
        for (int j = 0; j < 4; j++) acc[i][j] = (floatx4){0.f, 0.f, 0.f, 0.f};

    for (int k0 = 0; k0 < 1024; k0 += 32) {
        #pragma unroll
        for (int s = 0; s < 2; s++) {
            int v = tid + s * 256;
            int row = v >> 2, kb = v & 3;
            *reinterpret_cast<uint4*>(&As[(kb * 128 + row) * 8]) =
                *reinterpret_cast<const uint4*>(A + (size_t)row * 1024 + k0 + kb * 8);
            int brow = (row < 64) ? (bx * 64 + row) : (512 + bx * 64 + (row - 64));
            *reinterpret_cast<uint4*>(&Bs[(kb * 128 + row) * 8]) =
                *reinterpret_cast<const uint4*>(Be + (size_t)brow * 1024 + k0 + kb * 8);
        }
        __syncthreads();
        short8 af[4], bf[4];
        #pragma unroll
        for (int i = 0; i < 4; i++)
            af[i] = *reinterpret_cast<const short8*>(&As[(kq * 128 + m0 + i * 16 + lr) * 8]);
        #pragma unroll
        for (int j = 0; j < 4; j++) {
            int nn = (j < 2) ? (n0 + j * 16) : (64 + n0 + (j - 2) * 16);
            bf[j] = *reinterpret_cast<const short8*>(&Bs[(kq * 128 + nn + lr) * 8]);
        }
        #pragma unroll
        for (int i = 0; i < 4; i++)
            #pragma unroll
            for (int j = 0; j < 4; j++)
                acc[i][j] = __builtin_amdgcn_mfma_f32_16x16x32_bf16(af[i], bf[j], acc[i][j], 0, 0, 0);
        __syncthreads();
    }
    // epilogue: a = y * silu(z), y = acc[][0..1], z = acc[][2..3] (same g per lane)
    #pragma unroll
    for (int i = 0; i < 4; i++) {
        #pragma unroll
        for (int jy = 0; jy < 2; jy++) {
            floatx4 y = acc[i][jy], z = acc[i][jy + 2];
            #pragma unroll
            for (int r = 0; r < 4; r++) {
                float zz = z[r];
                float av = y[r] * (zz / (1.0f + __expf(-zz)));
                int m = m0 + i * 16 + kq * 4 + r;
                int g = bx * 64 + n0 + jy * 16 + lr;
                Act[(size_t)(row0 + m) * D_INT + g] = f2bf(av);
            }
        }
    }
}

// GEMM2: [rows x 512] * fc2[e]^T -> O2[rows x 1024] f32
// grid (8, 40): x = 128-wide d block, y = 128-row tile
__global__ __launch_bounds__(256) void gemm2_kernel(
    const u16* __restrict__ Act, const u16* __restrict__ fc2b,
    float* __restrict__ O2, const int* __restrict__ meta) {
    __shared__ u16 As[4096];
    __shared__ u16 Bs[4096];
    __shared__ int soff[9];
    int tid = threadIdx.x;
    if (tid < 9) soff[tid] = meta[tid];
    __syncthreads();
    int row0 = blockIdx.y * 128;
    if (row0 >= soff[8]) return;
    int e = 0;
    while (soff[e + 1] <= row0) e++;
    int bx = blockIdx.x;
    const u16* A  = Act + (size_t)row0 * 512;
    const u16* Be = fc2b + (size_t)e * 1024 * 512;

    int lane = tid & 63, w = tid >> 6;
    int m0 = (w >> 1) * 64, n0 = (w & 1) * 64;
    int lr = lane & 15, kq = lane >> 4;

    floatx4 acc[4][4];
    #pragma unroll
    for (int i = 0; i < 4; i++)
        #pragma unroll
        for (int j = 0; j < 4; j++) acc[i][j] = (floatx4){0.f, 0.f, 0.f, 0.f};

    for (int k0 = 0; k0 < 512; k0 += 32) {
        #pragma unroll
        for (int s = 0; s < 2; s++) {
            int v = tid + s * 256;
            int row = v >> 2, kb = v & 3;
            *reinterpret_cast<uint4*>(&As[(kb * 128 + row) * 8]) =
                *reinterpret_cast<const uint4*>(A + (size_t)row * 512 + k0 + kb * 8);
            *reinterpret_cast<uint4*>(&Bs[(kb * 128 + row) * 8]) =
                *reinterpret_cast<const uint4*>(Be + (size_t)(bx * 128 + row) * 512 + k0 + kb * 8);
        }
        __syncthreads();
        short8 af[4], bf[4];
        #pragma unroll
        for (int i = 0; i < 4; i++)
            af[i] = *reinterpret_cast<const short8*>(&As[(kq * 128 + m0 + i * 16 + lr) * 8]);
        #pragma unroll
        for (int j = 0; j < 4; j++)
            bf[j] = *reinterpret_cast<const short8*>(&Bs[(kq * 128 + n0 + j * 16 + lr) * 8]);
        #pragma unroll
        for (int i = 0; i < 4; i++)
            #pragma unroll
            for (int j = 0; j < 4; j++)
                acc[i][j] = __builtin_amdgcn_mfma_f32_16x16x32_bf16(af[i], bf[j], acc[i][j], 0, 0, 0);
        __syncthreads();
    }
    #pragma unroll
    for (int i = 0; i < 4; i++)
        #pragma unroll
        for (int j = 0; j < 4; j++) {
            #pragma unroll
            for (int r = 0; r < 4; r++) {
                int m = m0 + i * 16 + kq * 4 + r;
                int n = bx * 128 + n0 + j * 16 + lr;
                O2[(size_t)(row0 + m) * D_MODEL + n] = acc[i][j][r];
            }
        }
}

__global__ void combine_kernel(const float* __restrict__ O2,
                               const float* __restrict__ wts,
                               const int* __restrict__ row_of,
                               float* __restrict__ out) {
    int t = blockIdx.x;
    int tid = threadIdx.x;
    int r0 = row_of[2 * t], r1 = row_of[2 * t + 1];
    float w0 = wts[2 * t], w1 = wts[2 * t + 1];
    const floatx4* p0 = reinterpret_cast<const floatx4*>(O2 + (size_t)r0 * D_MODEL);
    const floatx4* p1 = reinterpret_cast<const floatx4*>(O2 + (size_t)r1 * D_MODEL);
    floatx4 v = w0 * p0[tid] + w1 * p1[tid];
    reinterpret_cast<floatx4*>(out + (size_t)t * D_MODEL)[tid] = v;
}

extern "C" void kernel_launch(void* const* d_in, const int* in_sizes, int n_in,
                              void* d_out, int out_size, void* d_ws, size_t ws_size,
                              hipStream_t stream) {
    const float* x       = (const float*)d_in[0];
    const float* wts     = (const float*)d_in[1];
    const int*   indices = (const int*)d_in[2];
    const int*   counts  = (const int*)d_in[3];
    const float* fc1     = (const float*)d_in[4];
    const float* fc2     = (const float*)d_in[5];
    float* out = (float*)d_out;
    char* ws = (char*)d_ws;

    int*  meta   = (int*)(ws + O_META);
    int*  row_of = (int*)(ws + O_ROWOF);
    u16*  Xg     = (u16*)(ws + O_XG);
    u16*  Act    = (u16*)(ws + O_ACT);
    float* O2    = (float*)(ws + O_O2);
    u16*  fc1b   = (u16*)(ws + O_FC1B);
    u16*  fc2b   = (u16*)(ws + O_FC2B);

    setup_kernel<<<1, 64, 0, stream>>>(counts, meta);
    convert_w<<<6144, 256, 0, stream>>>(fc1, fc2, fc1b, fc2b);
    dispatch_gather<<<NPAIR, 128, 0, stream>>>(x, indices, meta, row_of, Xg);
    gemm1_kernel<<<dim3(8, 40), 256, 0, stream>>>(Xg, fc1b, Act, meta);
    gemm2_kernel<<<dim3(8, 40), 256, 0, stream>>>(Act, fc2b, O2, meta);
    combine_kernel<<<N_TOK, 256, 0, stream>>>(O2, wts, row_of, out);
}

// Round 2
// 167.523 us; speedup vs baseline: 2.0633x; 2.0633x over previous
//
#include <hip/hip_runtime.h>

typedef unsigned short u16;
typedef unsigned int u32;
using short8  = __attribute__((ext_vector_type(8))) short;
using floatx4 = __attribute__((ext_vector_type(4))) float;

#define N_TOK   2048
#define D_MODEL 1024
#define D_INT   512
#define NE      8
#define NPAIR   (N_TOK * 2)
#define ROWS_PAD 5120   // >= 4096 + 8*127, multiple of 128

// ws layout (bytes)
#define O_META   0          // int meta[16]: [0..8]=off_pad
#define O_ROWOF  4096       // int row_of[4096]
#define O_XG     65536      // u16 Xg[5120*1024]
#define O_ACT    10551296   // u16 Act[5120*512]
#define O_O2     15794176   // float O2[5120*1024]
#define O_FC1B   36765696   // u16 fc1b[8*1024*1024]
#define O_FC2B   53542912   // u16 fc2b[8*1024*512]

static __device__ inline u16 f2bf(float f) {
    u32 u = __builtin_bit_cast(u32, f);
    u = (u + 0x7fffu + ((u >> 16) & 1u)) >> 16;
    return (u16)u;
}
static __device__ inline u32 pack2(float a, float b) {
    return (u32)f2bf(a) | ((u32)f2bf(b) << 16);
}

// Single-block deterministic routing: per-expert rank via Hillis-Steele scan.
// Replaces 4096 cross-XCD atomics (184 us) with one ~3 us block.
__global__ __launch_bounds__(256) void route_kernel(const int* __restrict__ indices,
                                                    const int* __restrict__ counts,
                                                    int* __restrict__ meta,
                                                    int* __restrict__ row_of) {
    __shared__ int cnt[256][NE];   // 8 KB
    __shared__ int off[NE];
    int t = threadIdx.x;
    int idx[16];
    #pragma unroll
    for (int i = 0; i < 16; i++) idx[i] = indices[t * 16 + i];
    int loc[NE];
    #pragma unroll
    for (int e = 0; e < NE; e++) {
        int c = 0;
        #pragma unroll
        for (int i = 0; i < 16; i++) c += (idx[i] == e);
        loc[e] = c;
        cnt[t][e] = c;
    }
    if (t == 0) {
        int acc = 0;
        #pragma unroll
        for (int e = 0; e < NE; e++) {
            off[e] = acc;
            meta[e] = acc;
            acc += ((counts[e] + 127) >> 7) << 7;
        }
        meta[8] = acc;
    }
    __syncthreads();
    // inclusive scan over threads, 8 experts in parallel
    for (int d = 1; d < 256; d <<= 1) {
        int v[NE];
        #pragma unroll
        for (int e = 0; e < NE; e++) v[e] = (t >= d) ? cnt[t - d][e] : 0;
        __syncthreads();
        #pragma unroll
        for (int e = 0; e < NE; e++) cnt[t][e] += v[e];
        __syncthreads();
    }
    // convert to exclusive (running) counts for this thread
    #pragma unroll
    for (int e = 0; e < NE; e++) cnt[t][e] -= loc[e];
    __syncthreads();
    #pragma unroll
    for (int i = 0; i < 16; i++) {
        int e = idx[i];
        int r = cnt[t][e]++;           // dynamic-indexed LDS, fine
        row_of[t * 16 + i] = off[e] + r;
    }
}

// One block per token: read x once (f32), write both top-k rows as bf16.
__global__ __launch_bounds__(128) void gather_kernel(const float* __restrict__ x,
                                                     const int* __restrict__ row_of,
                                                     u16* __restrict__ Xg) {
    int t = blockIdx.x;
    int tid = threadIdx.x;
    int r0 = row_of[2 * t], r1 = row_of[2 * t + 1];
    const floatx4* src = reinterpret_cast<const floatx4*>(x + (size_t)t * D_MODEL);
    floatx4 a = src[tid * 2];
    floatx4 b = src[tid * 2 + 1];
    uint4 o;
    o.x = pack2(a[0], a[1]); o.y = pack2(a[2], a[3]);
    o.z = pack2(b[0], b[1]); o.w = pack2(b[2], b[3]);
    *reinterpret_cast<uint4*>(Xg + (size_t)r0 * D_MODEL + tid * 8) = o;
    *reinterpret_cast<uint4*>(Xg + (size_t)r1 * D_MODEL + tid * 8) = o;
}

// fc1: 8*1024*1024 f32 -> bf16 ; fc2: 8*1024*512
__global__ void convert_w(const float* __restrict__ fc1, const float* __restrict__ fc2,
                          u16* __restrict__ fc1b, u16* __restrict__ fc2b) {
    size_t v = (size_t)blockIdx.x * 256 + threadIdx.x;   // vec8 id, total 1572864
    const float* src; u16* dst; size_t off;
    if (v < 1048576) { src = fc1; dst = fc1b; off = v * 8; }
    else             { src = fc2; dst = fc2b; off = (v - 1048576) * 8; }
    const floatx4* s4 = reinterpret_cast<const floatx4*>(src + off);
    floatx4 a = s4[0], b = s4[1];
    uint4 o;
    o.x = pack2(a[0], a[1]); o.y = pack2(a[2], a[3]);
    o.z = pack2(b[0], b[1]); o.w = pack2(b[2], b[3]);
    *reinterpret_cast<uint4*>(dst + off) = o;
}

// GEMM1: [rows x 1024] * fc1[e]^T -> h[rows x 1024]; a = y*silu(z) -> Act[rows x 512] bf16
// grid (8, 40): x = 64-wide g block, y = 128-row tile
__global__ __launch_bounds__(256) void gemm1_kernel(
    const u16* __restrict__ Xg, const u16* __restrict__ fc1b,
    u16* __restrict__ Act, const int* __restrict__ meta) {
    __shared__ u16 As[4096];   // [kb][row][8]
    __shared__ u16 Bs[4096];
    __shared__ int soff[9];
    int tid = threadIdx.x;
    if (tid < 9) soff[tid] = meta[tid];
    __syncthreads();
    int row0 = blockIdx.y * 128;
    if (row0 >= soff[8]) return;
    int e = 0;
    while (soff[e + 1] <= row0) e++;
    int bx = blockIdx.x;                       // g block: g in [bx*64, bx*64+64)
    const u16* A  = Xg + (size_t)row0 * 1024;
    const u16* Be = fc1b + (size_t)e * 1024 * 1024;

    int lane = tid & 63, w = tid >> 6;
    int m0 = (w >> 1) * 64, n0 = (w & 1) * 32;
    int lr = lane & 15, kq = lane >> 4;

    floatx4 acc[4][4];
    #pragma unroll
    for (int i = 0; i < 4; i++)
        #pragma unroll
        for (int j = 0; j < 4; j++) acc[i][j] = (floatx4){0.f, 0.f, 0.f, 0.f};

    for (int k0 = 0; k0 < 1024; k0 += 32) {
        #pragma unroll
        for (int s = 0; s < 2; s++) {
            int v = tid + s * 256;
            int row = v >> 2, kb = v & 3;
            *reinterpret_cast<uint4*>(&As[(kb * 128 + row) * 8]) =
                *reinterpret_cast<const uint4*>(A + (size_t)row * 1024 + k0 + kb * 8);
            int brow = (row < 64) ? (bx * 64 + row) : (512 + bx * 64 + (row - 64));
            *reinterpret_cast<uint4*>(&Bs[(kb * 128 + row) * 8]) =
                *reinterpret_cast<const uint4*>(Be + (size_t)brow * 1024 + k0 + kb * 8);
        }
        __syncthreads();
        short8 af[4], bf[4];
        #pragma unroll
        for (int i = 0; i < 4; i++)
            af[i] = *reinterpret_cast<const short8*>(&As[(kq * 128 + m0 + i * 16 + lr) * 8]);
        #pragma unroll
        for (int j = 0; j < 4; j++) {
            int nn = (j < 2) ? (n0 + j * 16) : (64 + n0 + (j - 2) * 16);
            bf[j] = *reinterpret_cast<const short8*>(&Bs[(kq * 128 + nn + lr) * 8]);
        }
        #pragma unroll
        for (int i = 0; i < 4; i++)
            #pragma unroll
            for (int j = 0; j < 4; j++)
                acc[i][j] = __builtin_amdgcn_mfma_f32_16x16x32_bf16(af[i], bf[j], acc[i][j], 0, 0, 0);
        __syncthreads();
    }
    // epilogue: a = y * silu(z), y = acc[][0..1], z = acc[][2..3] (same g per lane)
    #pragma unroll
    for (int i = 0; i < 4; i++) {
        #pragma unroll
        for (int jy = 0; jy < 2; jy++) {
            floatx4 y = acc[i][jy], z = acc[i][jy + 2];
            #pragma unroll
            for (int r = 0; r < 4; r++) {
                float zz = z[r];
                float av = y[r] * (zz / (1.0f + __expf(-zz)));
                int m = m0 + i * 16 + kq * 4 + r;
                int g = bx * 64 + n0 + jy * 16 + lr;
                Act[(size_t)(row0 + m) * D_INT + g] = f2bf(av);
            }
        }
    }
}

// GEMM2: [rows x 512] * fc2[e]^T -> O2[rows x 1024] f32
// grid (8, 40): x = 128-wide d block, y = 128-row tile
__global__ __launch_bounds__(256) void gemm2_kernel(
    const u16* __restrict__ Act, const u16* __restrict__ fc2b,
    float* __restrict__ O2, const int* __restrict__ meta) {
    __shared__ u16 As[4096];
    __shared__ u16 Bs[4096];
    __shared__ int soff[9];
    int tid = threadIdx.x;
    if (tid < 9) soff[tid] = meta[tid];
    __syncthreads();
    int row0 = blockIdx.y * 128;
    if (row0 >= soff[8]) return;
    int e = 0;
    while (soff[e + 1] <= row0) e++;
    int bx = blockIdx.x;
    const u16* A  = Act + (size_t)row0 * 512;
    const u16* Be = fc2b + (size_t)e * 1024 * 512;

    int lane = tid & 63, w = tid >> 6;
    int m0 = (w >> 1) * 64, n0 = (w & 1) * 64;
    int lr = lane & 15, kq = lane >> 4;

    floatx4 acc[4][4];
    #pragma unroll
    for (int i = 0; i < 4; i++)
        #pragma unroll
        for (int j = 0; j < 4; j++) acc[i][j] = (floatx4){0.f, 0.f, 0.f, 0.f};

    for (int k0 = 0; k0 < 512; k0 += 32) {
        #pragma unroll
        for (int s = 0; s < 2; s++) {
            int v = tid + s * 256;
            int row = v >> 2, kb = v & 3;
            *reinterpret_cast<uint4*>(&As[(kb * 128 + row) * 8]) =
                *reinterpret_cast<const uint4*>(A + (size_t)row * 512 + k0 + kb * 8);
            *reinterpret_cast<uint4*>(&Bs[(kb * 128 + row) * 8]) =
                *reinterpret_cast<const uint4*>(Be + (size_t)(bx * 128 + row) * 512 + k0 + kb * 8);
        }
        __syncthreads();
        short8 af[4], bf[4];
        #pragma unroll
        for (int i = 0; i < 4; i++)
            af[i] = *reinterpret_cast<const short8*>(&As[(kq * 128 + m0 + i * 16 + lr) * 8]);
        #pragma unroll
        for (int j = 0; j < 4; j++)
            bf[j] = *reinterpret_cast<const short8*>(&Bs[(kq * 128 + n0 + j * 16 + lr) * 8]);
        #pragma unroll
        for (int i = 0; i < 4; i++)
            #pragma unroll
            for (int j = 0; j < 4; j++)
                acc[i][j] = __builtin_amdgcn_mfma_f32_16x16x32_bf16(af[i], bf[j], acc[i][j], 0, 0, 0);
        __syncthreads();
    }
    #pragma unroll
    for (int i = 0; i < 4; i++)
        #pragma unroll
        for (int j = 0; j < 4; j++) {
            #pragma unroll
            for (int r = 0; r < 4; r++) {
                int m = m0 + i * 16 + kq * 4 + r;
                int n = bx * 128 + n0 + j * 16 + lr;
                O2[(size_t)(row0 + m) * D_MODEL + n] = acc[i][j][r];
            }
        }
}

__global__ void combine_kernel(const float* __restrict__ O2,
                               const float* __restrict__ wts,
                               const int* __restrict__ row_of,
                               float* __restrict__ out) {
    int t = blockIdx.x;
    int tid = threadIdx.x;
    int r0 = row_of[2 * t], r1 = row_of[2 * t + 1];
    float w0 = wts[2 * t], w1 = wts[2 * t + 1];
    const floatx4* p0 = reinterpret_cast<const floatx4*>(O2 + (size_t)r0 * D_MODEL);
    const floatx4* p1 = reinterpret_cast<const floatx4*>(O2 + (size_t)r1 * D_MODEL);
    floatx4 v = w0 * p0[tid] + w1 * p1[tid];
    reinterpret_cast<floatx4*>(out + (size_t)t * D_MODEL)[tid] = v;
}

extern "C" void kernel_launch(void* const* d_in, const int* in_sizes, int n_in,
                              void* d_out, int out_size, void* d_ws, size_t ws_size,
                              hipStream_t stream) {
    const float* x       = (const float*)d_in[0];
    const float* wts     = (const float*)d_in[1];
    const int*   indices = (const int*)d_in[2];
    const int*   counts  = (const int*)d_in[3];
    const float* fc1     = (const float*)d_in[4];
    const float* fc2     = (const float*)d_in[5];
    float* out = (float*)d_out;
    char* ws = (char*)d_ws;

    int*  meta   = (int*)(ws + O_META);
    int*  row_of = (int*)(ws + O_ROWOF);
    u16*  Xg     = (u16*)(ws + O_XG);
    u16*  Act    = (u16*)(ws + O_ACT);
    float* O2    = (float*)(ws + O_O2);
    u16*  fc1b   = (u16*)(ws + O_FC1B);
    u16*  fc2b   = (u16*)(ws + O_FC2B);

    route_kernel<<<1, 256, 0, stream>>>(indices, counts, meta, row_of);
    convert_w<<<6144, 256, 0, stream>>>(fc1, fc2, fc1b, fc2b);
    gather_kernel<<<N_TOK, 128, 0, stream>>>(x, row_of, Xg);
    gemm1_kernel<<<dim3(8, 40), 256, 0, stream>>>(Xg, fc1b, Act, meta);
    gemm2_kernel<<<dim3(8, 40), 256, 0, stream>>>(Act, fc2b, O2, meta);
    combine_kernel<<<N_TOK, 256, 0, stream>>>(O2, wts, row_of, out);
}

// Round 3
// 163.563 us; speedup vs baseline: 2.1133x; 1.0242x over previous
//
#include <hip/hip_runtime.h>

typedef unsigned short u16;
typedef unsigned int u32;
using short8  = __attribute__((ext_vector_type(8))) short;
using floatx4 = __attribute__((ext_vector_type(4))) float;

#define N_TOK   2048
#define D_MODEL 1024
#define D_INT   512
#define NE      8
#define ROWS_PAD 5120

// ws layout (bytes)
#define O_META   0          // int meta[16]: [0..8]=off_pad
#define O_ROWOF  4096       // int row_of[4096]
#define O_PAIR   20480      // int pair_of[5120]
#define O_XG     65536      // u16 Xg[5120*1024]
#define O_ACT    10551296   // u16 Act[5120*512]
#define O_FC1B   36765696   // u16 fc1b[8*1024*1024]
#define O_FC2B   53542912   // u16 fc2b[8*1024*512]

static __device__ inline u16 f2bf(float f) {
    u32 u = __builtin_bit_cast(u32, f);
    u = (u + 0x7fffu + ((u >> 16) & 1u)) >> 16;
    return (u16)u;
}
static __device__ inline u32 pack2(float a, float b) {
    return (u32)f2bf(a) | ((u32)f2bf(b) << 16);
}
static __device__ inline void glds16(const u16* g, u16* l) {
    __builtin_amdgcn_global_load_lds(
        (const __attribute__((address_space(1))) void*)g,
        (__attribute__((address_space(3))) void*)l, 16, 0, 0);
}

// Single-block deterministic routing + row->pair inverse map.
__global__ __launch_bounds__(256) void route_kernel(const int* __restrict__ indices,
                                                    const int* __restrict__ counts,
                                                    int* __restrict__ meta,
                                                    int* __restrict__ row_of,
                                                    int* __restrict__ pair_of) {
    __shared__ int cnt[256][NE];
    __shared__ int off[NE];
    int t = threadIdx.x;
    #pragma unroll
    for (int i = 0; i < 20; i++) pair_of[t * 20 + i] = -1;   // 5120 = ROWS_PAD
    int idx[16];
    #pragma unroll
    for (int i = 0; i < 16; i++) idx[i] = indices[t * 16 + i];
    int loc[NE];
    #pragma unroll
    for (int e = 0; e < NE; e++) {
        int c = 0;
        #pragma unroll
        for (int i = 0; i < 16; i++) c += (idx[i] == e);
        loc[e] = c;
        cnt[t][e] = c;
    }
    if (t == 0) {
        int acc = 0;
        #pragma unroll
        for (int e = 0; e < NE; e++) {
            off[e] = acc;
            meta[e] = acc;
            acc += ((counts[e] + 127) >> 7) << 7;
        }
        meta[8] = acc;
    }
    __syncthreads();
    for (int d = 1; d < 256; d <<= 1) {
        int v[NE];
        #pragma unroll
        for (int e = 0; e < NE; e++) v[e] = (t >= d) ? cnt[t - d][e] : 0;
        __syncthreads();
        #pragma unroll
        for (int e = 0; e < NE; e++) cnt[t][e] += v[e];
        __syncthreads();
    }
    #pragma unroll
    for (int e = 0; e < NE; e++) cnt[t][e] -= loc[e];
    __syncthreads();
    #pragma unroll
    for (int i = 0; i < 16; i++) {
        int e = idx[i];
        int r = cnt[t][e]++;
        int row = off[e] + r;
        row_of[t * 16 + i] = row;
        pair_of[row] = t * 16 + i;
    }
}

// One block per token: read x once (f32), write both top-k rows as bf16.
__global__ __launch_bounds__(128) void gather_kernel(const float* __restrict__ x,
                                                     const int* __restrict__ row_of,
                                                     u16* __restrict__ Xg) {
    int t = blockIdx.x;
    int tid = threadIdx.x;
    int r0 = row_of[2 * t], r1 = row_of[2 * t + 1];
    const floatx4* src = reinterpret_cast<const floatx4*>(x + (size_t)t * D_MODEL);
    floatx4 a = src[tid * 2];
    floatx4 b = src[tid * 2 + 1];
    uint4 o;
    o.x = pack2(a[0], a[1]); o.y = pack2(a[2], a[3]);
    o.z = pack2(b[0], b[1]); o.w = pack2(b[2], b[3]);
    *reinterpret_cast<uint4*>(Xg + (size_t)r0 * D_MODEL + tid * 8) = o;
    *reinterpret_cast<uint4*>(Xg + (size_t)r1 * D_MODEL + tid * 8) = o;
}

__global__ void convert_w(const float* __restrict__ fc1, const float* __restrict__ fc2,
                          u16* __restrict__ fc1b, u16* __restrict__ fc2b) {
    size_t v = (size_t)blockIdx.x * 256 + threadIdx.x;
    const float* src; u16* dst; size_t off;
    if (v < 1048576) { src = fc1; dst = fc1b; off = v * 8; }
    else             { src = fc2; dst = fc2b; off = (v - 1048576) * 8; }
    const floatx4* s4 = reinterpret_cast<const floatx4*>(src + off);
    floatx4 a = s4[0], b = s4[1];
    uint4 o;
    o.x = pack2(a[0], a[1]); o.y = pack2(a[2], a[3]);
    o.z = pack2(b[0], b[1]); o.w = pack2(b[2], b[3]);
    *reinterpret_cast<uint4*>(dst + off) = o;
}

// GEMM1: Xg[rows x 1024] * fc1[e]^T; a = y*silu(z) -> Act[rows x 512] bf16.
// LDS tiles row-major [128][32] u16, 16B slots XOR-swizzled (slot = kb ^ ((row>>1)&3)),
// staged via global_load_lds width=16 (lane-contiguous dest, swizzle on source addr).
__global__ __launch_bounds__(256) void gemm1_kernel(
    const u16* __restrict__ Xg, const u16* __restrict__ fc1b,
    u16* __restrict__ Act, const int* __restrict__ meta) {
    __shared__ u16 As[4096];
    __shared__ u16 Bs[4096];
    __shared__ int soff[9];
    int tid = threadIdx.x;
    if (tid < 9) soff[tid] = meta[tid];
    __syncthreads();
    int row0 = blockIdx.y * 128;
    if (row0 >= soff[8]) return;
    int e = 0;
    while (soff[e + 1] <= row0) e++;
    int bx = blockIdx.x;
    const u16* A  = Xg + (size_t)row0 * 1024;
    const u16* Be = fc1b + (size_t)e * 1024 * 1024;

    int lane = tid & 63, w = tid >> 6;
    int m0 = (w >> 1) * 64, n0 = (w & 1) * 32;
    int lr = lane & 15, kq = lane >> 4;
    int ka = ((kq ^ ((lr >> 1) & 3)) * 8);   // swizzled 16B-slot offset (u16 units)

    // staging: slot v -> LDS bytes v*16; holds global chunk kb = (v&3)^((row>>1)&3)
    int v0 = tid, v1 = tid + 256;
    int r0s = v0 >> 2, kb0 = (v0 & 3) ^ ((r0s >> 1) & 3);
    int r1s = v1 >> 2, kb1 = (v1 & 3) ^ ((r1s >> 1) & 3);
    int brow0 = (r0s < 64) ? bx * 64 + r0s : 448 + bx * 64 + r0s;  // y rows then z rows
    int brow1 = (r1s < 64) ? bx * 64 + r1s : 448 + bx * 64 + r1s;
    u16* lA0 = As + (w * 64) * 8;           // wave-uniform base, s=0
    u16* lA1 = As + (w * 64 + 256) * 8;     // s=1
    u16* lB0 = Bs + (w * 64) * 8;
    u16* lB1 = Bs + (w * 64 + 256) * 8;
    const u16* gA0 = A + (size_t)r0s * 1024 + kb0 * 8;
    const u16* gA1 = A + (size_t)r1s * 1024 + kb1 * 8;
    const u16* gB0 = Be + (size_t)brow0 * 1024 + kb0 * 8;
    const u16* gB1 = Be + (size_t)brow1 * 1024 + kb1 * 8;

    floatx4 acc[4][4];
    #pragma unroll
    for (int i = 0; i < 4; i++)
        #pragma unroll
        for (int j = 0; j < 4; j++) acc[i][j] = (floatx4){0.f, 0.f, 0.f, 0.f};

    for (int k0 = 0; k0 < 1024; k0 += 32) {
        glds16(gA0 + k0, lA0);
        glds16(gA1 + k0, lA1);
        glds16(gB0 + k0, lB0);
        glds16(gB1 + k0, lB1);
        __syncthreads();
        short8 af[4], bf[4];
        #pragma unroll
        for (int i = 0; i < 4; i++)
            af[i] = *reinterpret_cast<const short8*>(&As[(m0 + i * 16 + lr) * 32 + ka]);
        #pragma unroll
        for (int j = 0; j < 4; j++) {
            int nn = (j < 2) ? (n0 + j * 16) : (64 + n0 + (j - 2) * 16);
            bf[j] = *reinterpret_cast<const short8*>(&Bs[(nn + lr) * 32 + ka]);
        }
        #pragma unroll
        for (int i = 0; i < 4; i++)
            #pragma unroll
            for (int j = 0; j < 4; j++)
                acc[i][j] = __builtin_amdgcn_mfma_f32_16x16x32_bf16(af[i], bf[j], acc[i][j], 0, 0, 0);
        __syncthreads();
    }
    #pragma unroll
    for (int i = 0; i < 4; i++) {
        #pragma unroll
        for (int jy = 0; jy < 2; jy++) {
            floatx4 y = acc[i][jy], z = acc[i][jy + 2];
            #pragma unroll
            for (int r = 0; r < 4; r++) {
                float zz = z[r];
                float av = y[r] * (zz / (1.0f + __expf(-zz)));
                int m = m0 + i * 16 + kq * 4 + r;
                int g = bx * 64 + n0 + jy * 16 + lr;
                Act[(size_t)(row0 + m) * D_INT + g] = f2bf(av);
            }
        }
    }
}

// GEMM2: Act[rows x 512] * fc2[e]^T, fused combine: out[t] += w * O2row (f32 atomics).
__global__ __launch_bounds__(256) void gemm2_kernel(
    const u16* __restrict__ Act, const u16* __restrict__ fc2b,
    float* __restrict__ out, const int* __restrict__ meta,
    const int* __restrict__ pair_of, const float* __restrict__ wts) {
    __shared__ u16 As[4096];
    __shared__ u16 Bs[4096];
    __shared__ int soff[9];
    __shared__ int sPair[128];
    __shared__ float sW[128];
    int tid = threadIdx.x;
    if (tid < 9) soff[tid] = meta[tid];
    __syncthreads();
    int row0 = blockIdx.y * 128;
    if (row0 >= soff[8]) return;
    int e = 0;
    while (soff[e + 1] <= row0) e++;
    int bx = blockIdx.x;
    const u16* A  = Act + (size_t)row0 * 512;
    const u16* Be = fc2b + (size_t)e * 1024 * 512;

    int lane = tid & 63, w = tid >> 6;
    int m0 = (w >> 1) * 64, n0 = (w & 1) * 64;
    int lr = lane & 15, kq = lane >> 4;
    int ka = ((kq ^ ((lr >> 1) & 3)) * 8);

    int v0 = tid, v1 = tid + 256;
    int r0s = v0 >> 2, kb0 = (v0 & 3) ^ ((r0s >> 1) & 3);
    int r1s = v1 >> 2, kb1 = (v1 & 3) ^ ((r1s >> 1) & 3);
    u16* lA0 = As + (w * 64) * 8;
    u16* lA1 = As + (w * 64 + 256) * 8;
    u16* lB0 = Bs + (w * 64) * 8;
    u16* lB1 = Bs + (w * 64 + 256) * 8;
    const u16* gA0 = A + (size_t)r0s * 512 + kb0 * 8;
    const u16* gA1 = A + (size_t)r1s * 512 + kb1 * 8;
    const u16* gB0 = Be + (size_t)(bx * 128 + r0s) * 512 + kb0 * 8;
    const u16* gB1 = Be + (size_t)(bx * 128 + r1s) * 512 + kb1 * 8;

    floatx4 acc[4][4];
    #pragma unroll
    for (int i = 0; i < 4; i++)
        #pragma unroll
        for (int j = 0; j < 4; j++) acc[i][j] = (floatx4){0.f, 0.f, 0.f, 0.f};

    for (int k0 = 0; k0 < 512; k0 += 32) {
        glds16(gA0 + k0, lA0);
        glds16(gA1 + k0, lA1);
        glds16(gB0 + k0, lB0);
        glds16(gB1 + k0, lB1);
        __syncthreads();
        short8 af[4], bf[4];
        #pragma unroll
        for (int i = 0; i < 4; i++)
            af[i] = *reinterpret_cast<const short8*>(&As[(m0 + i * 16 + lr) * 32 + ka]);
        #pragma unroll
        for (int j = 0; j < 4; j++)
            bf[j] = *reinterpret_cast<const short8*>(&Bs[(n0 + j * 16 + lr) * 32 + ka]);
        #pragma unroll
        for (int i = 0; i < 4; i++)
            #pragma unroll
            for (int j = 0; j < 4; j++)
                acc[i][j] = __builtin_amdgcn_mfma_f32_16x16x32_bf16(af[i], bf[j], acc[i][j], 0, 0, 0);
        __syncthreads();
    }
    if (tid < 128) {
        int p = pair_of[row0 + tid];
        sPair[tid] = p;
        sW[tid] = (p >= 0) ? wts[p] : 0.f;
    }
    __syncthreads();
    #pragma unroll
    for (int i = 0; i < 4; i++)
        #pragma unroll
        for (int r = 0; r < 4; r++) {
            int m = m0 + i * 16 + kq * 4 + r;
            int p = sPair[m];
            if (p >= 0) {
                float wgt = sW[m];
                float* dst = out + (size_t)(p >> 1) * D_MODEL + bx * 128;
                #pragma unroll
                for (int j = 0; j < 4; j++)
                    atomicAdd(dst + n0 + j * 16 + lr, wgt * acc[i][j][r]);
            }
        }
}

extern "C" void kernel_launch(void* const* d_in, const int* in_sizes, int n_in,
                              void* d_out, int out_size, void* d_ws, size_t ws_size,
                              hipStream_t stream) {
    const float* x       = (const float*)d_in[0];
    const float* wts     = (const float*)d_in[1];
    const int*   indices = (const int*)d_in[2];
    const int*   counts  = (const int*)d_in[3];
    const float* fc1     = (const float*)d_in[4];
    const float* fc2     = (const float*)d_in[5];
    float* out = (float*)d_out;
    char* ws = (char*)d_ws;

    int*  meta    = (int*)(ws + O_META);
    int*  row_of  = (int*)(ws + O_ROWOF);
    int*  pair_of = (int*)(ws + O_PAIR);
    u16*  Xg      = (u16*)(ws + O_XG);
    u16*  Act     = (u16*)(ws + O_ACT);
    u16*  fc1b    = (u16*)(ws + O_FC1B);
    u16*  fc2b    = (u16*)(ws + O_FC2B);

    hipMemsetAsync(d_out, 0, (size_t)out_size * sizeof(float), stream);
    route_kernel<<<1, 256, 0, stream>>>(indices, counts, meta, row_of, pair_of);
    convert_w<<<6144, 256, 0, stream>>>(fc1, fc2, fc1b, fc2b);
    gather_kernel<<<N_TOK, 128, 0, stream>>>(x, row_of, Xg);
    gemm1_kernel<<<dim3(8, 40), 256, 0, stream>>>(Xg, fc1b, Act, meta);
    gemm2_kernel<<<dim3(8, 40), 256, 0, stream>>>(Act, fc2b, out, meta, pair_of, wts);
}

// Round 4
// 159.091 us; speedup vs baseline: 2.1727x; 1.0281x over previous
//
#include <hip/hip_runtime.h>

typedef unsigned short u16;
typedef unsigned int u32;
using short8  = __attribute__((ext_vector_type(8))) short;
using floatx4 = __attribute__((ext_vector_type(4))) float;

#define N_TOK   2048
#define D_MODEL 1024
#define D_INT   512
#define NE      8
#define ROWS_PAD 5120

// ws layout (bytes)
#define O_TOK    0          // int tok[5120]
#define O_WROW   24576      // float wrow[5120]
#define O_XG     65536      // u16 Xg[5120*1024]
#define O_ACT    10551296   // u16 Act[5120*512]
#define O_FC1B   36765696   // u16 fc1b[8*1024*1024]
#define O_FC2B   53542912   // u16 fc2b[8*1024*512]

static __device__ inline u16 f2bf(float f) {
    u32 u = __builtin_bit_cast(u32, f);
    u = (u + 0x7fffu + ((u >> 16) & 1u)) >> 16;
    return (u16)u;
}
static __device__ inline u32 pack2(float a, float b) {
    return (u32)f2bf(a) | ((u32)f2bf(b) << 16);
}
static __device__ inline void glds16(const u16* g, u16* l) {
    __builtin_amdgcn_global_load_lds(
        (const __attribute__((address_space(1))) void*)g,
        (__attribute__((address_space(3))) void*)l, 16, 0, 0);
}

// Fused prep: blocks [0,6144) convert weights f32->bf16; [6144,8192) route+gather
// one token each (rank via scan of L2-resident indices — no atomics, no serial
// route kernel); [8192,8704) zero d_out for gemm2's atomic combine.
__global__ __launch_bounds__(256) void prep_kernel(
    const float* __restrict__ x, const float* __restrict__ wts,
    const int* __restrict__ indices, const int* __restrict__ counts,
    const float* __restrict__ fc1, const float* __restrict__ fc2,
    u16* __restrict__ fc1b, u16* __restrict__ fc2b,
    u16* __restrict__ Xg, int* __restrict__ tok, float* __restrict__ wrow,
    float* __restrict__ out) {
    int b = blockIdx.x, tid = threadIdx.x;
    if (b < 6144) {
        size_t v = (size_t)b * 256 + tid;
        const float* src; u16* dst; size_t off;
        if (v < 1048576) { src = fc1; dst = fc1b; off = v * 8; }
        else             { src = fc2; dst = fc2b; off = (v - 1048576) * 8; }
        const floatx4* s4 = reinterpret_cast<const floatx4*>(src + off);
        floatx4 a = s4[0], bb = s4[1];
        uint4 o;
        o.x = pack2(a[0], a[1]); o.y = pack2(a[2], a[3]);
        o.z = pack2(bb[0], bb[1]); o.w = pack2(bb[2], bb[3]);
        *reinterpret_cast<uint4*>(dst + off) = o;
        return;
    }
    if (b < 8192) {
        int t = b - 6144;
        int off[NE];
        {
            int acc = 0;
            #pragma unroll
            for (int e = 0; e < NE; e++) { off[e] = acc; acc += ((counts[e] + 127) >> 7) << 7; }
        }
        int e0 = indices[2 * t], e1 = indices[2 * t + 1];
        __shared__ int s0, s1;
        if (tid == 0) { s0 = 0; s1 = 0; }
        __syncthreads();
        int c0 = 0, c1 = 0;
        const int4* ip = reinterpret_cast<const int4*>(indices);
        #pragma unroll
        for (int i = 0; i < 4; i++) {
            int4 vv = ip[tid * 4 + i];
            int q = tid * 16 + i * 4;
            c0 += (q + 0 < 2 * t && vv.x == e0) + (q + 1 < 2 * t && vv.y == e0)
                + (q + 2 < 2 * t && vv.z == e0) + (q + 3 < 2 * t && vv.w == e0);
            c1 += (q + 0 <= 2 * t && vv.x == e1) + (q + 1 <= 2 * t && vv.y == e1)
                + (q + 2 <= 2 * t && vv.z == e1) + (q + 3 <= 2 * t && vv.w == e1);
        }
        if (c0) atomicAdd(&s0, c0);
        if (c1) atomicAdd(&s1, c1);
        __syncthreads();
        int r0 = off[e0] + s0;
        int r1 = off[e1] + s1;
        if (tid == 0) {
            tok[r0] = t; tok[r1] = t;
            wrow[r0] = wts[2 * t]; wrow[r1] = wts[2 * t + 1];
        }
        const floatx4* src = reinterpret_cast<const floatx4*>(x + (size_t)t * D_MODEL);
        floatx4 a = src[tid];
        uint2 o;
        o.x = pack2(a[0], a[1]); o.y = pack2(a[2], a[3]);
        *reinterpret_cast<uint2*>(Xg + (size_t)r0 * D_MODEL + tid * 4) = o;
        *reinterpret_cast<uint2*>(Xg + (size_t)r1 * D_MODEL + tid * 4) = o;
        return;
    }
    {   // zero d_out: 512 blocks x 1024 float4
        int z = b - 8192;
        floatx4* dst = reinterpret_cast<floatx4*>(out) + (size_t)z * 1024;
        #pragma unroll
        for (int i = 0; i < 4; i++) dst[i * 256 + tid] = (floatx4){0.f, 0.f, 0.f, 0.f};
        return;
    }
}

// GEMM1: Xg[rows x 1024] * fc1[e]^T; a = y*silu(z) -> Act[rows x 512] bf16.
__global__ __launch_bounds__(256) void gemm1_kernel(
    const u16* __restrict__ Xg, const u16* __restrict__ fc1b,
    u16* __restrict__ Act, const int* __restrict__ counts) {
    __shared__ u16 As[4096];
    __shared__ u16 Bs[4096];
    int tid = threadIdx.x;
    int soff[NE + 1];
    {
        int acc = 0;
        #pragma unroll
        for (int e2 = 0; e2 < NE; e2++) { soff[e2] = acc; acc += ((counts[e2] + 127) >> 7) << 7; }
        soff[NE] = acc;
    }
    int row0 = blockIdx.y * 128;
    if (row0 >= soff[NE]) return;
    int e = 0;
    while (soff[e + 1] <= row0) e++;
    int bx = blockIdx.x;
    const u16* A  = Xg + (size_t)row0 * 1024;
    const u16* Be = fc1b + (size_t)e * 1024 * 1024;

    int lane = tid & 63, w = tid >> 6;
    int m0 = (w >> 1) * 64, n0 = (w & 1) * 32;
    int lr = lane & 15, kq = lane >> 4;
    int ka = ((kq ^ ((lr >> 1) & 3)) * 8);

    int v0 = tid, v1 = tid + 256;
    int r0s = v0 >> 2, kb0 = (v0 & 3) ^ ((r0s >> 1) & 3);
    int r1s = v1 >> 2, kb1 = (v1 & 3) ^ ((r1s >> 1) & 3);
    int brow0 = (r0s < 64) ? bx * 64 + r0s : 448 + bx * 64 + r0s;
    int brow1 = (r1s < 64) ? bx * 64 + r1s : 448 + bx * 64 + r1s;
    u16* lA0 = As + (w * 64) * 8;
    u16* lA1 = As + (w * 64 + 256) * 8;
    u16* lB0 = Bs + (w * 64) * 8;
    u16* lB1 = Bs + (w * 64 + 256) * 8;
    const u16* gA0 = A + (size_t)r0s * 1024 + kb0 * 8;
    const u16* gA1 = A + (size_t)r1s * 1024 + kb1 * 8;
    const u16* gB0 = Be + (size_t)brow0 * 1024 + kb0 * 8;
    const u16* gB1 = Be + (size_t)brow1 * 1024 + kb1 * 8;

    floatx4 acc[4][4];
    #pragma unroll
    for (int i = 0; i < 4; i++)
        #pragma unroll
        for (int j = 0; j < 4; j++) acc[i][j] = (floatx4){0.f, 0.f, 0.f, 0.f};

    for (int k0 = 0; k0 < 1024; k0 += 32) {
        glds16(gA0 + k0, lA0);
        glds16(gA1 + k0, lA1);
        glds16(gB0 + k0, lB0);
        glds16(gB1 + k0, lB1);
        __syncthreads();
        short8 af[4], bf[4];
        #pragma unroll
        for (int i = 0; i < 4; i++)
            af[i] = *reinterpret_cast<const short8*>(&As[(m0 + i * 16 + lr) * 32 + ka]);
        #pragma unroll
        for (int j = 0; j < 4; j++) {
            int nn = (j < 2) ? (n0 + j * 16) : (64 + n0 + (j - 2) * 16);
            bf[j] = *reinterpret_cast<const short8*>(&Bs[(nn + lr) * 32 + ka]);
        }
        #pragma unroll
        for (int i = 0; i < 4; i++)
            #pragma unroll
            for (int j = 0; j < 4; j++)
                acc[i][j] = __builtin_amdgcn_mfma_f32_16x16x32_bf16(af[i], bf[j], acc[i][j], 0, 0, 0);
        __syncthreads();
    }
    #pragma unroll
    for (int i = 0; i < 4; i++) {
        #pragma unroll
        for (int jy = 0; jy < 2; jy++) {
            floatx4 y = acc[i][jy], z = acc[i][jy + 2];
            #pragma unroll
            for (int r = 0; r < 4; r++) {
                float zz = z[r];
                float av = y[r] * (zz / (1.0f + __expf(-zz)));
                int m = m0 + i * 16 + kq * 4 + r;
                int g = bx * 64 + n0 + jy * 16 + lr;
                Act[(size_t)(row0 + m) * D_INT + g] = f2bf(av);
            }
        }
    }
}

// GEMM2: Act[rows x 512] * fc2[e]^T, fused combine via f32 atomics into zeroed out.
__global__ __launch_bounds__(256) void gemm2_kernel(
    const u16* __restrict__ Act, const u16* __restrict__ fc2b,
    float* __restrict__ out, const int* __restrict__ counts,
    const int* __restrict__ tok, const float* __restrict__ wrow) {
    __shared__ u16 As[4096];
    __shared__ u16 Bs[4096];
    __shared__ int sTok[128];
    __shared__ float sW[128];
    int tid = threadIdx.x;
    int soff[NE + 1];
    int cnt[NE];
    {
        int acc = 0;
        #pragma unroll
        for (int e2 = 0; e2 < NE; e2++) {
            soff[e2] = acc; cnt[e2] = counts[e2];
            acc += ((cnt[e2] + 127) >> 7) << 7;
        }
        soff[NE] = acc;
    }
    int row0 = blockIdx.y * 128;
    if (row0 >= soff[NE]) return;
    int e = 0;
    while (soff[e + 1] <= row0) e++;
    int bx = blockIdx.x;
    const u16* A  = Act + (size_t)row0 * 512;
    const u16* Be = fc2b + (size_t)e * 1024 * 512;

    int lane = tid & 63, w = tid >> 6;
    int m0 = (w >> 1) * 64, n0 = (w & 1) * 64;
    int lr = lane & 15, kq = lane >> 4;
    int ka = ((kq ^ ((lr >> 1) & 3)) * 8);

    int v0 = tid, v1 = tid + 256;
    int r0s = v0 >> 2, kb0 = (v0 & 3) ^ ((r0s >> 1) & 3);
    int r1s = v1 >> 2, kb1 = (v1 & 3) ^ ((r1s >> 1) & 3);
    u16* lA0 = As + (w * 64) * 8;
    u16* lA1 = As + (w * 64 + 256) * 8;
    u16* lB0 = Bs + (w * 64) * 8;
    u16* lB1 = Bs + (w * 64 + 256) * 8;
    const u16* gA0 = A + (size_t)r0s * 512 + kb0 * 8;
    const u16* gA1 = A + (size_t)r1s * 512 + kb1 * 8;
    const u16* gB0 = Be + (size_t)(bx * 128 + r0s) * 512 + kb0 * 8;
    const u16* gB1 = Be + (size_t)(bx * 128 + r1s) * 512 + kb1 * 8;

    floatx4 acc[4][4];
    #pragma unroll
    for (int i = 0; i < 4; i++)
        #pragma unroll
        for (int j = 0; j < 4; j++) acc[i][j] = (floatx4){0.f, 0.f, 0.f, 0.f};

    for (int k0 = 0; k0 < 512; k0 += 32) {
        glds16(gA0 + k0, lA0);
        glds16(gA1 + k0, lA1);
        glds16(gB0 + k0, lB0);
        glds16(gB1 + k0, lB1);
        __syncthreads();
        short8 af[4], bf[4];
        #pragma unroll
        for (int i = 0; i < 4; i++)
            af[i] = *reinterpret_cast<const short8*>(&As[(m0 + i * 16 + lr) * 32 + ka]);
        #pragma unroll
        for (int j = 0; j < 4; j++)
            bf[j] = *reinterpret_cast<const short8*>(&Bs[(n0 + j * 16 + lr) * 32 + ka]);
        #pragma unroll
        for (int i = 0; i < 4; i++)
            #pragma unroll
            for (int j = 0; j < 4; j++)
                acc[i][j] = __builtin_amdgcn_mfma_f32_16x16x32_bf16(af[i], bf[j], acc[i][j], 0, 0, 0);
        __syncthreads();
    }
    if (tid < 128) {
        int g = row0 + tid;
        bool val = (g - soff[e]) < cnt[e];
        sTok[tid] = val ? tok[g] : -1;
        sW[tid]   = val ? wrow[g] : 0.f;
    }
    __syncthreads();
    #pragma unroll
    for (int i = 0; i < 4; i++)
        #pragma unroll
        for (int r = 0; r < 4; r++) {
            int m = m0 + i * 16 + kq * 4 + r;
            int t = sTok[m];
            if (t >= 0) {
                float wgt = sW[m];
                float* dst = out + (size_t)t * D_MODEL + bx * 128;
                #pragma unroll
                for (int j = 0; j < 4; j++)
                    atomicAdd(dst + n0 + j * 16 + lr, wgt * acc[i][j][r]);
            }
        }
}

extern "C" void kernel_launch(void* const* d_in, const int* in_sizes, int n_in,
                              void* d_out, int out_size, void* d_ws, size_t ws_size,
                              hipStream_t stream) {
    const float* x       = (const float*)d_in[0];
    const float* wts     = (const float*)d_in[1];
    const int*   indices = (const int*)d_in[2];
    const int*   counts  = (const int*)d_in[3];
    const float* fc1     = (const float*)d_in[4];
    const float* fc2     = (const float*)d_in[5];
    float* out = (float*)d_out;
    char* ws = (char*)d_ws;

    int*   tok  = (int*)(ws + O_TOK);
    float* wrow = (float*)(ws + O_WROW);
    u16*   Xg   = (u16*)(ws + O_XG);
    u16*   Act  = (u16*)(ws + O_ACT);
    u16*   fc1b = (u16*)(ws + O_FC1B);
    u16*   fc2b = (u16*)(ws + O_FC2B);

    prep_kernel<<<8704, 256, 0, stream>>>(x, wts, indices, counts, fc1, fc2,
                                          fc1b, fc2b, Xg, tok, wrow, out);
    gemm1_kernel<<<dim3(8, 40), 256, 0, stream>>>(Xg, fc1b, Act, counts);
    gemm2_kernel<<<dim3(8, 40), 256, 0, stream>>>(Act, fc2b, out, counts, tok, wrow);
}

// Round 5
// 151.602 us; speedup vs baseline: 2.2800x; 1.0494x over previous
//
#include <hip/hip_runtime.h>

typedef unsigned short u16;
typedef unsigned int u32;
using short8  = __attribute__((ext_vector_type(8))) short;
using floatx4 = __attribute__((ext_vector_type(4))) float;

#define N_TOK   2048
#define D_MODEL 1024
#define D_INT   512
#define NE      8

// ws layout (bytes)
#define O_TOK    0          // int tok[5120]
#define O_WROW   24576      // float wrow[5120]
#define O_XG     65536      // u16 Xg[5120*1024]
#define O_ACT    10551296   // u16 Act[5120*512]
#define O_FC1B   36765696   // u16 fc1b[8*1024*1024]
#define O_FC2B   53542912   // u16 fc2b[8*1024*512]

static __device__ inline u16 f2bf(float f) {
    u32 u = __builtin_bit_cast(u32, f);
    u = (u + 0x7fffu + ((u >> 16) & 1u)) >> 16;
    return (u16)u;
}
static __device__ inline u32 pack2(float a, float b) {
    return (u32)f2bf(a) | ((u32)f2bf(b) << 16);
}
static __device__ inline void glds16(const u16* g, u16* l) {
    __builtin_amdgcn_global_load_lds(
        (const __attribute__((address_space(1))) void*)g,
        (__attribute__((address_space(3))) void*)l, 16, 0, 0);
}

// Fused prep: [0,6144) convert weights f32->bf16; [6144,8192) route+gather one
// token each; [8192,8704) zero d_out. Row-pad quantum = 64.
__global__ __launch_bounds__(256) void prep_kernel(
    const float* __restrict__ x, const float* __restrict__ wts,
    const int* __restrict__ indices, const int* __restrict__ counts,
    const float* __restrict__ fc1, const float* __restrict__ fc2,
    u16* __restrict__ fc1b, u16* __restrict__ fc2b,
    u16* __restrict__ Xg, int* __restrict__ tok, float* __restrict__ wrow,
    float* __restrict__ out) {
    int b = blockIdx.x, tid = threadIdx.x;
    if (b < 6144) {
        size_t v = (size_t)b * 256 + tid;
        const float* src; u16* dst; size_t off;
        if (v < 1048576) { src = fc1; dst = fc1b; off = v * 8; }
        else             { src = fc2; dst = fc2b; off = (v - 1048576) * 8; }
        const floatx4* s4 = reinterpret_cast<const floatx4*>(src + off);
        floatx4 a = s4[0], bb = s4[1];
        uint4 o;
        o.x = pack2(a[0], a[1]); o.y = pack2(a[2], a[3]);
        o.z = pack2(bb[0], bb[1]); o.w = pack2(bb[2], bb[3]);
        *reinterpret_cast<uint4*>(dst + off) = o;
        return;
    }
    if (b < 8192) {
        int t = b - 6144;
        int off[NE];
        {
            int acc = 0;
            #pragma unroll
            for (int e = 0; e < NE; e++) { off[e] = acc; acc += ((counts[e] + 63) >> 6) << 6; }
        }
        int e0 = indices[2 * t], e1 = indices[2 * t + 1];
        __shared__ int s0, s1;
        if (tid == 0) { s0 = 0; s1 = 0; }
        __syncthreads();
        int c0 = 0, c1 = 0;
        const int4* ip = reinterpret_cast<const int4*>(indices);
        #pragma unroll
        for (int i = 0; i < 4; i++) {
            int4 vv = ip[tid * 4 + i];
            int q = tid * 16 + i * 4;
            c0 += (q + 0 < 2 * t && vv.x == e0) + (q + 1 < 2 * t && vv.y == e0)
                + (q + 2 < 2 * t && vv.z == e0) + (q + 3 < 2 * t && vv.w == e0);
            c1 += (q + 0 <= 2 * t && vv.x == e1) + (q + 1 <= 2 * t && vv.y == e1)
                + (q + 2 <= 2 * t && vv.z == e1) + (q + 3 <= 2 * t && vv.w == e1);
        }
        if (c0) atomicAdd(&s0, c0);
        if (c1) atomicAdd(&s1, c1);
        __syncthreads();
        int r0 = off[e0] + s0;
        int r1 = off[e1] + s1;
        if (tid == 0) {
            tok[r0] = t; tok[r1] = t;
            wrow[r0] = wts[2 * t]; wrow[r1] = wts[2 * t + 1];
        }
        const floatx4* src = reinterpret_cast<const floatx4*>(x + (size_t)t * D_MODEL);
        floatx4 a = src[tid];
        uint2 o;
        o.x = pack2(a[0], a[1]); o.y = pack2(a[2], a[3]);
        *reinterpret_cast<uint2*>(Xg + (size_t)r0 * D_MODEL + tid * 4) = o;
        *reinterpret_cast<uint2*>(Xg + (size_t)r1 * D_MODEL + tid * 4) = o;
        return;
    }
    {
        int z = b - 8192;
        floatx4* dst = reinterpret_cast<floatx4*>(out) + (size_t)z * 1024;
        #pragma unroll
        for (int i = 0; i < 4; i++) dst[i * 256 + tid] = (floatx4){0.f, 0.f, 0.f, 0.f};
        return;
    }
}

// GEMM1: 64-row x 64-g tile (y+z = 128 B-rows), BK=64, grid (8,72) = 576 blocks.
// LDS [row][8 slots x 8 u16], slot = kb ^ (row&7): glds16 octet = one 128B line,
// ds_read_b128 octet covers all 32 banks (conflict-free).
__global__ __launch_bounds__(256) void gemm1_kernel(
    const u16* __restrict__ Xg, const u16* __restrict__ fc1b,
    u16* __restrict__ Act, const int* __restrict__ counts) {
    __shared__ u16 As[64 * 64];
    __shared__ u16 Bs[128 * 64];
    int tid = threadIdx.x;
    int soff[NE + 1];
    {
        int acc = 0;
        #pragma unroll
        for (int e2 = 0; e2 < NE; e2++) { soff[e2] = acc; acc += ((counts[e2] + 63) >> 6) << 6; }
        soff[NE] = acc;
    }
    int row0 = blockIdx.y * 64;
    if (row0 >= soff[NE]) return;
    int e = 0;
    while (soff[e + 1] <= row0) e++;
    int bx = blockIdx.x;
    const u16* A  = Xg + (size_t)row0 * 1024;
    const u16* Be = fc1b + (size_t)e * 1024 * 1024;

    int lane = tid & 63, w = tid >> 6;
    int m0 = (w >> 1) * 32, n0 = (w & 1) * 32;
    int lr = lane & 15, kq = lane >> 4;

    const u16* gA[2]; u16* lA[2];
    #pragma unroll
    for (int j = 0; j < 2; j++) {
        int v = tid + j * 256;
        int r = v >> 3, kb = (v & 7) ^ (r & 7);
        gA[j] = A + (size_t)r * 1024 + kb * 8;
        lA[j] = As + (w * 64 + j * 256) * 8;
    }
    const u16* gB[4]; u16* lB[4];
    #pragma unroll
    for (int j = 0; j < 4; j++) {
        int v = tid + j * 256;
        int r = v >> 3, kb = (v & 7) ^ (r & 7);
        int grow = (r < 64) ? (bx * 64 + r) : (448 + bx * 64 + r);
        gB[j] = Be + (size_t)grow * 1024 + kb * 8;
        lB[j] = Bs + (w * 64 + j * 256) * 8;
    }

    floatx4 aY[2][2], aZ[2][2];
    #pragma unroll
    for (int i = 0; i < 2; i++)
        #pragma unroll
        for (int j = 0; j < 2; j++) {
            aY[i][j] = (floatx4){0.f, 0.f, 0.f, 0.f};
            aZ[i][j] = (floatx4){0.f, 0.f, 0.f, 0.f};
        }

    for (int k0 = 0; k0 < 1024; k0 += 64) {
        glds16(gA[0] + k0, lA[0]); glds16(gA[1] + k0, lA[1]);
        glds16(gB[0] + k0, lB[0]); glds16(gB[1] + k0, lB[1]);
        glds16(gB[2] + k0, lB[2]); glds16(gB[3] + k0, lB[3]);
        __syncthreads();
        #pragma unroll
        for (int ks = 0; ks < 2; ks++) {
            int sw = ((ks * 4 + kq) ^ (lr & 7)) * 8;
            short8 af[2], by[2], bz[2];
            #pragma unroll
            for (int i = 0; i < 2; i++)
                af[i] = *reinterpret_cast<const short8*>(&As[(m0 + i * 16 + lr) * 64 + sw]);
            #pragma unroll
            for (int j = 0; j < 2; j++) {
                by[j] = *reinterpret_cast<const short8*>(&Bs[(n0 + j * 16 + lr) * 64 + sw]);
                bz[j] = *reinterpret_cast<const short8*>(&Bs[(64 + n0 + j * 16 + lr) * 64 + sw]);
            }
            #pragma unroll
            for (int i = 0; i < 2; i++)
                #pragma unroll
                for (int j = 0; j < 2; j++) {
                    aY[i][j] = __builtin_amdgcn_mfma_f32_16x16x32_bf16(af[i], by[j], aY[i][j], 0, 0, 0);
                    aZ[i][j] = __builtin_amdgcn_mfma_f32_16x16x32_bf16(af[i], bz[j], aZ[i][j], 0, 0, 0);
                }
        }
        __syncthreads();
    }
    #pragma unroll
    for (int i = 0; i < 2; i++)
        #pragma unroll
        for (int j = 0; j < 2; j++) {
            floatx4 y = aY[i][j], z = aZ[i][j];
            #pragma unroll
            for (int r = 0; r < 4; r++) {
                float zz = z[r];
                float av = y[r] * (zz / (1.0f + __expf(-zz)));
                int m = m0 + i * 16 + kq * 4 + r;
                int g = bx * 64 + n0 + j * 16 + lr;
                Act[(size_t)(row0 + m) * D_INT + g] = f2bf(av);
            }
        }
}

// GEMM2: 64-row x 128-d tile, BK=64, grid (8,72); fused combine via f32 atomics.
__global__ __launch_bounds__(256) void gemm2_kernel(
    const u16* __restrict__ Act, const u16* __restrict__ fc2b,
    float* __restrict__ out, const int* __restrict__ counts,
    const int* __restrict__ tok, const float* __restrict__ wrow) {
    __shared__ u16 As[64 * 64];
    __shared__ u16 Bs[128 * 64];
    __shared__ int sTok[64];
    __shared__ float sW[64];
    int tid = threadIdx.x;
    int soff[NE + 1];
    {
        int acc = 0;
        #pragma unroll
        for (int e2 = 0; e2 < NE; e2++) { soff[e2] = acc; acc += ((counts[e2] + 63) >> 6) << 6; }
        soff[NE] = acc;
    }
    int row0 = blockIdx.y * 64;
    if (row0 >= soff[NE]) return;
    int e = 0;
    while (soff[e + 1] <= row0) e++;
    int bx = blockIdx.x;
    const u16* A  = Act + (size_t)row0 * 512;
    const u16* Be = fc2b + (size_t)e * 1024 * 512;

    int lane = tid & 63, w = tid >> 6;
    int m0 = (w >> 1) * 32, n0 = (w & 1) * 64;
    int lr = lane & 15, kq = lane >> 4;

    const u16* gA[2]; u16* lA[2];
    #pragma unroll
    for (int j = 0; j < 2; j++) {
        int v = tid + j * 256;
        int r = v >> 3, kb = (v & 7) ^ (r & 7);
        gA[j] = A + (size_t)r * 512 + kb * 8;
        lA[j] = As + (w * 64 + j * 256) * 8;
    }
    const u16* gB[4]; u16* lB[4];
    #pragma unroll
    for (int j = 0; j < 4; j++) {
        int v = tid + j * 256;
        int r = v >> 3, kb = (v & 7) ^ (r & 7);
        gB[j] = Be + (size_t)(bx * 128 + r) * 512 + kb * 8;
        lB[j] = Bs + (w * 64 + j * 256) * 8;
    }

    floatx4 acc[2][4];
    #pragma unroll
    for (int i = 0; i < 2; i++)
        #pragma unroll
        for (int j = 0; j < 4; j++) acc[i][j] = (floatx4){0.f, 0.f, 0.f, 0.f};

    for (int k0 = 0; k0 < 512; k0 += 64) {
        glds16(gA[0] + k0, lA[0]); glds16(gA[1] + k0, lA[1]);
        glds16(gB[0] + k0, lB[0]); glds16(gB[1] + k0, lB[1]);
        glds16(gB[2] + k0, lB[2]); glds16(gB[3] + k0, lB[3]);
        __syncthreads();
        #pragma unroll
        for (int ks = 0; ks < 2; ks++) {
            int sw = ((ks * 4 + kq) ^ (lr & 7)) * 8;
            short8 af[2], bf[4];
            #pragma unroll
            for (int i = 0; i < 2; i++)
                af[i] = *reinterpret_cast<const short8*>(&As[(m0 + i * 16 + lr) * 64 + sw]);
            #pragma unroll
            for (int j = 0; j < 4; j++)
                bf[j] = *reinterpret_cast<const short8*>(&Bs[(n0 + j * 16 + lr) * 64 + sw]);
            #pragma unroll
            for (int i = 0; i < 2; i++)
                #pragma unroll
                for (int j = 0; j < 4; j++)
                    acc[i][j] = __builtin_amdgcn_mfma_f32_16x16x32_bf16(af[i], bf[j], acc[i][j], 0, 0, 0);
        }
        __syncthreads();
    }
    if (tid < 64) {
        int g = row0 + tid;
        bool val = (g - soff[e]) < counts[e];
        sTok[tid] = val ? tok[g] : -1;
        sW[tid]   = val ? wrow[g] : 0.f;
    }
    __syncthreads();
    #pragma unroll
    for (int i = 0; i < 2; i++)
        #pragma unroll
        for (int r = 0; r < 4; r++) {
            int m = m0 + i * 16 + kq * 4 + r;
            int t = sTok[m];
            if (t >= 0) {
                float wgt = sW[m];
                float* dst = out + (size_t)t * D_MODEL + bx * 128;
                #pragma unroll
                for (int j = 0; j < 4; j++)
                    atomicAdd(dst + n0 + j * 16 + lr, wgt * acc[i][j][r]);
            }
        }
}

extern "C" void kernel_launch(void* const* d_in, const int* in_sizes, int n_in,
                              void* d_out, int out_size, void* d_ws, size_t ws_size,
                              hipStream_t stream) {
    const float* x       = (const float*)d_in[0];
    const float* wts     = (const float*)d_in[1];
    const int*   indices = (const int*)d_in[2];
    const int*   counts  = (const int*)d_in[3];
    const float* fc1     = (const float*)d_in[4];
    const float* fc2     = (const float*)d_in[5];
    float* out = (float*)d_out;
    char* ws = (char*)d_ws;

    int*   tok  = (int*)(ws + O_TOK);
    float* wrow = (float*)(ws + O_WROW);
    u16*   Xg   = (u16*)(ws + O_XG);
    u16*   Act  = (u16*)(ws + O_ACT);
    u16*   fc1b = (u16*)(ws + O_FC1B);
    u16*   fc2b = (u16*)(ws + O_FC2B);

    prep_kernel<<<8704, 256, 0, stream>>>(x, wts, indices, counts, fc1, fc2,
                                          fc1b, fc2b, Xg, tok, wrow, out);
    gemm1_kernel<<<dim3(8, 72), 256, 0, stream>>>(Xg, fc1b, Act, counts);
    gemm2_kernel<<<dim3(8, 72), 256, 0, stream>>>(Act, fc2b, out, counts, tok, wrow);
}